// Round 4
// baseline (176.491 us; speedup 1.0000x reference)
//
#include <hip/hip_runtime.h>
#include <math.h>

#define CC 256
#define NTOK 4096
#define NHEADS 8
#define HD 32
#define FFD 1024
#define LN_EPS 1e-5f
#define QSCALE 0.17677669529663687f  // 1/sqrt(32)

typedef __bf16 bf16x8 __attribute__((ext_vector_type(8)));
typedef float f32x4 __attribute__((ext_vector_type(4)));

__device__ __forceinline__ unsigned short f2bf(float f) {
    unsigned u = __builtin_bit_cast(unsigned, f);
    u += 0x7fff + ((u >> 16) & 1);   // RNE
    return (unsigned short)(u >> 16);
}
__device__ __forceinline__ float bf2f(unsigned short h) {
    unsigned u = ((unsigned)h) << 16;
    return __builtin_bit_cast(float, u);
}
__device__ __forceinline__ void gload16(const unsigned short* g, unsigned short* l) {
    __builtin_amdgcn_global_load_lds(
        (const __attribute__((address_space(1))) unsigned int*)(const void*)g,
        (__attribute__((address_space(3))) unsigned int*)(void*)l, 16, 0, 0);
}

// ---------------- LayerNorm: one wave per token, fp32 in -> bf16 out -------
__global__ void ln_kernel(const float* __restrict__ x, const float* __restrict__ g,
                          const float* __restrict__ b, unsigned short* __restrict__ out) {
    int wave = threadIdx.x >> 6;
    int lane = threadIdx.x & 63;
    int tok = blockIdx.x * 4 + wave;
    const float4 v = ((const float4*)(x + (size_t)tok * CC))[lane];
    float s  = v.x + v.y + v.z + v.w;
    float ss = v.x * v.x + v.y * v.y + v.z * v.z + v.w * v.w;
    #pragma unroll
    for (int o = 32; o > 0; o >>= 1) { s += __shfl_xor(s, o); ss += __shfl_xor(ss, o); }
    float m   = s * (1.0f / CC);
    float var = ss * (1.0f / CC) - m * m;
    float r   = rsqrtf(var + LN_EPS);
    float4 gv = ((const float4*)g)[lane];
    float4 bv = ((const float4*)b)[lane];
    ushort4 o4;
    o4.x = f2bf((v.x - m) * r * gv.x + bv.x);
    o4.y = f2bf((v.y - m) * r * gv.y + bv.y);
    o4.z = f2bf((v.z - m) * r * gv.z + bv.z);
    o4.w = f2bf((v.w - m) * r * gv.w + bv.w);
    ((ushort4*)(out + (size_t)tok * CC))[lane] = o4;
}

// ---------------- Merged setup: all weight transposes + bias fuse ----------
__global__ void setup_kernel(const float* __restrict__ wq, const float* __restrict__ wk,
                             const float* __restrict__ wv, const float* __restrict__ wo,
                             const float* __restrict__ w1, const float* __restrict__ w2,
                             const float* __restrict__ bq, const float* __restrict__ bk,
                             const float* __restrict__ bv,
                             unsigned short* __restrict__ wt_qkv, unsigned short* __restrict__ wo_t,
                             unsigned short* __restrict__ w1_t, unsigned short* __restrict__ w2_t,
                             float* __restrict__ bqkv) {
    int id = blockIdx.x;
    int t = threadIdx.x;
    if (id == 192) {
        bqkv[t]       = bq[t] * QSCALE;
        bqkv[256 + t] = bk[t];
        bqkv[512 + t] = bv[t];
        return;
    }
    const float* src; unsigned short* dst;
    int Kd, N, rowoff = 0, bx, by; float scale = 1.0f;
    if (id < 16)       { src = wq; dst = wt_qkv; Kd = 256;  N = 256;  scale = QSCALE; int l = id;       bx = l & 3;  by = l >> 2; }
    else if (id < 32)  { src = wk; dst = wt_qkv; Kd = 256;  N = 256;  rowoff = 256;   int l = id - 16;  bx = l & 3;  by = l >> 2; }
    else if (id < 48)  { src = wv; dst = wt_qkv; Kd = 256;  N = 256;  rowoff = 512;   int l = id - 32;  bx = l & 3;  by = l >> 2; }
    else if (id < 64)  { src = wo; dst = wo_t;   Kd = 256;  N = 256;                  int l = id - 48;  bx = l & 3;  by = l >> 2; }
    else if (id < 128) { src = w1; dst = w1_t;   Kd = 256;  N = 1024;                 int l = id - 64;  bx = l & 15; by = l >> 4; }
    else               { src = w2; dst = w2_t;   Kd = 1024; N = 256;                  int l = id - 128; bx = l & 3;  by = l >> 2; }
    int n0 = bx * 64, k0 = by * 64;
    __shared__ float tile[64][65];
    int cc = t & 63, rb = t >> 6;
    #pragma unroll
    for (int i = 0; i < 16; i++) {
        int r = rb + i * 4;
        tile[r][cc] = src[(size_t)(k0 + r) * N + n0 + cc];
    }
    __syncthreads();
    int n = t >> 2;
    #pragma unroll
    for (int i = 0; i < 8; i++) {
        int p = (t & 3) + i * 4;
        unsigned lo = f2bf(tile[2 * p][n] * scale);
        unsigned hi = f2bf(tile[2 * p + 1][n] * scale);
        *(unsigned*)(dst + (size_t)(rowoff + n0 + n) * Kd + k0 + 2 * p) = lo | (hi << 16);
    }
}

// ---------------- full-K-resident bf16 MFMA GEMM (K=256) ------------------
// Whole A(BMx256) and B(BNx256) tiles staged once as 8 slabs of [rows][64B];
// one barrier, then 8 unbarriered MFMA phases. 4 waves (2x2).
template<int BM, int BN, int ACT, bool ADD_RES, bool OUT_BF16>
__global__ __launch_bounds__(256) void gemm_res(
    const unsigned short* __restrict__ A, const unsigned short* __restrict__ Bt,
    const float* __restrict__ bias, const float* __restrict__ res,
    void* __restrict__ Cm, int N) {
    constexpr int KD = 256;
    constexpr int WM = BM / 2, WN = BN / 2;
    constexpr int MF = WM / 16, NF = WN / 16;
    __shared__ unsigned short lds[(BM + BN) * KD];
    unsigned short* Bl = lds + BM * KD;
    const int t = threadIdx.x;
    const int lane = t & 63, w = t >> 6;
    const int wr = w >> 1, wc = w & 1;
    const int bm = blockIdx.y * BM, bn = blockIdx.x * BN;
    const int fr = lane & 15, sq = lane >> 4;

    #pragma unroll
    for (int i = 0; i < BM * 32 / 256; i++) {          // A: 8 slabs x BM x 4 chunks
        int c = t + i * 256;
        int kk = c / (BM * 4), r = (c % (BM * 4)) >> 2, jj = c & 3;
        gload16(A + (size_t)(bm + r) * KD + kk * 32 + jj * 8, lds + c * 8);
    }
    #pragma unroll
    for (int i = 0; i < BN * 32 / 256; i++) {
        int c = t + i * 256;
        int kk = c / (BN * 4), r = (c % (BN * 4)) >> 2, jj = c & 3;
        gload16(Bt + (size_t)(bn + r) * KD + kk * 32 + jj * 8, Bl + c * 8);
    }
    __syncthreads();

    f32x4 acc[MF][NF] = {};
    #pragma unroll
    for (int kk = 0; kk < 8; kk++) {
        const char* La = (const char*)lds + kk * BM * 64;
        const char* Lb = (const char*)Bl  + kk * BN * 64;
        bf16x8 af[MF], bfr[NF];
        #pragma unroll
        for (int i = 0; i < MF; i++)
            af[i] = *(const bf16x8*)(La + (wr * WM + i * 16 + fr) * 64 + sq * 16);
        #pragma unroll
        for (int j = 0; j < NF; j++)
            bfr[j] = *(const bf16x8*)(Lb + (wc * WN + j * 16 + fr) * 64 + sq * 16);
        #pragma unroll
        for (int i = 0; i < MF; i++)
            #pragma unroll
            for (int j = 0; j < NF; j++)
                acc[i][j] = __builtin_amdgcn_mfma_f32_16x16x32_bf16(af[i], bfr[j], acc[i][j], 0, 0, 0);
    }
    #pragma unroll
    for (int i = 0; i < MF; i++) {
        int row0 = bm + wr * WM + i * 16 + sq * 4;
        #pragma unroll
        for (int j = 0; j < NF; j++) {
            int col = bn + wc * WN + j * 16 + fr;
            float bvv = bias[col];
            #pragma unroll
            for (int r = 0; r < 4; r++) {
                float v = acc[i][j][r] + bvv;
                if constexpr (ACT == 1) v = 0.5f * v * (1.0f + erff(v * 0.70710678118654752f));
                if constexpr (ADD_RES) v += res[(size_t)(row0 + r) * N + col];
                if constexpr (OUT_BF16)
                    ((unsigned short*)Cm)[(size_t)(row0 + r) * N + col] = f2bf(v);
                else
                    ((float*)Cm)[(size_t)(row0 + r) * N + col] = v;
            }
        }
    }
}

// ---------------- double-buffered GEMM, BK=64 (for K=1024 FF2) -------------
template<int BM, int BN, int KD, int ACT, bool ADD_RES, bool OUT_BF16>
__global__ __launch_bounds__(256) void gemm_db(
    const unsigned short* __restrict__ A, const unsigned short* __restrict__ Bt,
    const float* __restrict__ bias, const float* __restrict__ res,
    void* __restrict__ Cm, int N) {
    constexpr int WM = BM / 2, WN = BN / 2;
    constexpr int MF = WM / 16, NF = WN / 16;
    constexpr int NIT = KD / 64;
    __shared__ unsigned short lds[2][(BM + BN) * 64];
    const int t = threadIdx.x;
    const int lane = t & 63, w = t >> 6;
    const int wr = w >> 1, wc = w & 1;
    const int bm = blockIdx.y * BM, bn = blockIdx.x * BN;
    const int fr = lane & 15, sq = lane >> 4;

    auto stage = [&](int it, int buf) {
        unsigned short* La = lds[buf];
        unsigned short* Lb = lds[buf] + BM * 64;
        #pragma unroll
        for (int i = 0; i < BM * 8 / 256; i++) {       // 2 slabs x BM x 4 chunks
            int c = t + i * 256;
            int kk = c / (BM * 4), r = (c % (BM * 4)) >> 2, jj = c & 3;
            gload16(A + (size_t)(bm + r) * KD + it * 64 + kk * 32 + jj * 8, La + c * 8);
        }
        #pragma unroll
        for (int i = 0; i < BN * 8 / 256; i++) {
            int c = t + i * 256;
            int kk = c / (BN * 4), r = (c % (BN * 4)) >> 2, jj = c & 3;
            gload16(Bt + (size_t)(bn + r) * KD + it * 64 + kk * 32 + jj * 8, Lb + c * 8);
        }
    };

    f32x4 acc[MF][NF] = {};
    stage(0, 0);
    for (int it = 0; it < NIT; ++it) {
        const int buf = it & 1;
        __syncthreads();                    // drains stage(it)
        if (it + 1 < NIT) stage(it + 1, buf ^ 1);
        #pragma unroll
        for (int kk = 0; kk < 2; kk++) {
            const char* La = (const char*)(lds[buf]) + kk * BM * 64;
            const char* Lb = (const char*)(lds[buf] + BM * 64) + kk * BN * 64;
            bf16x8 af[MF], bfr[NF];
            #pragma unroll
            for (int i = 0; i < MF; i++)
                af[i] = *(const bf16x8*)(La + (wr * WM + i * 16 + fr) * 64 + sq * 16);
            #pragma unroll
            for (int j = 0; j < NF; j++)
                bfr[j] = *(const bf16x8*)(Lb + (wc * WN + j * 16 + fr) * 64 + sq * 16);
            #pragma unroll
            for (int i = 0; i < MF; i++)
                #pragma unroll
                for (int j = 0; j < NF; j++)
                    acc[i][j] = __builtin_amdgcn_mfma_f32_16x16x32_bf16(af[i], bfr[j], acc[i][j], 0, 0, 0);
        }
    }
    #pragma unroll
    for (int i = 0; i < MF; i++) {
        int row0 = bm + wr * WM + i * 16 + sq * 4;
        #pragma unroll
        for (int j = 0; j < NF; j++) {
            int col = bn + wc * WN + j * 16 + fr;
            float bvv = bias[col];
            #pragma unroll
            for (int r = 0; r < 4; r++) {
                float v = acc[i][j][r] + bvv;
                if constexpr (ACT == 1) v = 0.5f * v * (1.0f + erff(v * 0.70710678118654752f));
                if constexpr (ADD_RES) v += res[(size_t)(row0 + r) * N + col];
                if constexpr (OUT_BF16)
                    ((unsigned short*)Cm)[(size_t)(row0 + r) * N + col] = f2bf(v);
                else
                    ((float*)Cm)[(size_t)(row0 + r) * N + col] = v;
            }
        }
    }
}

// ---------------- Attention: one wave per token, coalesced -----------------
// lane = head(3b) x e(3b); lane covers dims [h*32 + e*16 .. ) -- i.e. 4 dims
// via ushort4 at col lane*4. K/V row loads are 512B/wave contiguous.
// Scores: 8-lane-group shfl reduce; lane e owns neighbors n == e (mod 8).
__global__ __launch_bounds__(256) void attn_kernel(
    const unsigned short* __restrict__ qkv, const float* __restrict__ rpb,
    unsigned short* __restrict__ ctx) {
    int wave = threadIdx.x >> 6;
    int lane = threadIdx.x & 63;
    int tok  = blockIdx.x * 4 + wave;
    int i = tok >> 6, j = tok & 63;
    int gi = i >> 1, ri = i & 1;
    int gj = j >> 1, rj = j & 1;
    int si = min(max(gi - 3, 0), 25);
    int sj = min(max(gj - 3, 0), 25);
    int h = lane >> 3, e = lane & 7;

    ushort4 qv = *(const ushort4*)(qkv + (size_t)tok * 768 + (lane << 2));
    float q0 = bf2f(qv.x), q1 = bf2f(qv.y), q2 = bf2f(qv.z), q3 = bf2f(qv.w);

    int krow[7], jcol[7];
    #pragma unroll
    for (int a = 0; a < 7; a++) {
        krow[a] = ((si + a) * 2 + ri) * 64;
        jcol[a] = (sj + a) * 2 + rj;
    }
    const float* rb = rpb + h * 169 + (si - gi + 6) * 13 + (sj - gj + 6);

    float sc[7];
    #pragma unroll
    for (int t2 = 0; t2 < 7; t2++) sc[t2] = -1e30f;

    #pragma unroll
    for (int n = 0; n < 49; n++) {
        int kt = krow[n / 7] + jcol[n % 7];
        const ushort4 kv = *(const ushort4*)(qkv + (size_t)kt * 768 + 256 + (lane << 2));
        float s = q0 * bf2f(kv.x) + q1 * bf2f(kv.y) + q2 * bf2f(kv.z) + q3 * bf2f(kv.w);
        s += __shfl_xor(s, 1); s += __shfl_xor(s, 2); s += __shfl_xor(s, 4);
        s += rb[(n / 7) * 13 + (n % 7)];
        if (e == (n & 7)) sc[n >> 3] = s;
    }
    float mx = sc[0];
    #pragma unroll
    for (int t2 = 1; t2 < 7; t2++) mx = fmaxf(mx, sc[t2]);
    mx = fmaxf(mx, __shfl_xor(mx, 1));
    mx = fmaxf(mx, __shfl_xor(mx, 2));
    mx = fmaxf(mx, __shfl_xor(mx, 4));
    float pr[7], sum = 0.0f;
    #pragma unroll
    for (int t2 = 0; t2 < 7; t2++) { pr[t2] = __expf(sc[t2] - mx); sum += pr[t2]; }
    sum += __shfl_xor(sum, 1); sum += __shfl_xor(sum, 2); sum += __shfl_xor(sum, 4);
    float inv = 1.0f / sum;
    #pragma unroll
    for (int t2 = 0; t2 < 7; t2++) pr[t2] *= inv;

    float a0 = 0.0f, a1 = 0.0f, a2 = 0.0f, a3 = 0.0f;
    #pragma unroll
    for (int n = 0; n < 49; n++) {
        int kt = krow[n / 7] + jcol[n % 7];
        float p = __shfl(pr[n >> 3], n & 7, 8);
        const ushort4 vv = *(const ushort4*)(qkv + (size_t)kt * 768 + 512 + (lane << 2));
        a0 += p * bf2f(vv.x); a1 += p * bf2f(vv.y);
        a2 += p * bf2f(vv.z); a3 += p * bf2f(vv.w);
    }
    ushort4 o;
    o.x = f2bf(a0); o.y = f2bf(a1); o.z = f2bf(a2); o.w = f2bf(a3);
    ((ushort4*)(ctx + (size_t)tok * 256))[lane] = o;
}

extern "C" void kernel_launch(void* const* d_in, const int* in_sizes, int n_in,
                              void* d_out, int out_size, void* d_ws, size_t ws_size,
                              hipStream_t stream) {
    const float* x     = (const float*)d_in[0];
    const float* ln1_g = (const float*)d_in[1];
    const float* ln1_b = (const float*)d_in[2];
    const float* wq    = (const float*)d_in[3];
    const float* bq    = (const float*)d_in[4];
    const float* wk    = (const float*)d_in[5];
    const float* bk    = (const float*)d_in[6];
    const float* wv    = (const float*)d_in[7];
    const float* bv    = (const float*)d_in[8];
    const float* rpb   = (const float*)d_in[9];
    const float* wo    = (const float*)d_in[10];
    const float* bo    = (const float*)d_in[11];
    const float* ln2_g = (const float*)d_in[12];
    const float* ln2_b = (const float*)d_in[13];
    const float* w1    = (const float*)d_in[14];
    const float* b1    = (const float*)d_in[15];
    const float* w2    = (const float*)d_in[16];
    const float* b2    = (const float*)d_in[17];

    char* wsb = (char*)d_ws;
    unsigned short* hs_bf  = (unsigned short*)(wsb);                    // 2 MB
    unsigned short* qkv_bf = (unsigned short*)(wsb + (2u << 20));       // 6 MB
    unsigned short* ctx_bf = (unsigned short*)(wsb + (8u << 20));       // 2 MB
    float*          hs2    = (float*)(wsb + (10u << 20));               // 4 MB
    unsigned short* y1_bf  = (unsigned short*)(wsb + (14u << 20));      // 2 MB
    unsigned short* gm_bf  = (unsigned short*)(wsb + (16u << 20));      // 8 MB
    unsigned short* wt_qkv = (unsigned short*)(wsb + (24u << 20));      // 768x256
    unsigned short* wo_t   = wt_qkv + 768 * 256;                        // 256x256
    unsigned short* w1_t   = wo_t + 256 * 256;                          // 1024x256
    unsigned short* w2_t   = w1_t + 1024 * 256;                         // 256x1024
    float*          bqkv   = (float*)(w2_t + 256 * 1024);               // 768

    // 0. merged weight transpose/convert + bias fuse
    setup_kernel<<<193, 256, 0, stream>>>(wq, wk, wv, wo, w1, w2, bq, bk, bv,
                                          wt_qkv, wo_t, w1_t, w2_t, bqkv);
    // 1. hs = LN1(x)
    ln_kernel<<<NTOK / 4, 256, 0, stream>>>(x, ln1_g, ln1_b, hs_bf);
    // 2. fused QKV: [4096,768] = hs @ [wq|wk|wv]
    gemm_res<64, 64, 0, false, true><<<dim3(12, 64), 256, 0, stream>>>(
        hs_bf, wt_qkv, bqkv, nullptr, qkv_bf, 768);
    // 3. neighborhood attention
    attn_kernel<<<NTOK / 4, 256, 0, stream>>>(qkv_bf, rpb, ctx_bf);
    // 4. hs2 = x + ctx@wo + bo  (fp32)
    gemm_res<32, 64, 0, true, false><<<dim3(4, 128), 256, 0, stream>>>(
        ctx_bf, wo_t, bo, x, hs2, 256);
    // 5. y1 = LN2(hs2)
    ln_kernel<<<NTOK / 4, 256, 0, stream>>>(hs2, ln2_g, ln2_b, y1_bf);
    // 6. gmid = gelu(y1@w1 + b1)
    gemm_res<64, 64, 1, false, true><<<dim3(16, 64), 256, 0, stream>>>(
        y1_bf, w1_t, b1, nullptr, gm_bf, 1024);
    // 7. out = hs2 + gmid@w2 + b2  (fp32)
    gemm_db<32, 64, 1024, 0, true, false><<<dim3(4, 128), 256, 0, stream>>>(
        gm_bf, w2_t, b2, hs2, (float*)d_out, 256);
}

// Round 5
// 136.622 us; speedup vs baseline: 1.2918x; 1.2918x over previous
//
#include <hip/hip_runtime.h>
#include <math.h>

#define CC 256
#define NTOK 4096
#define NHEADS 8
#define HD 32
#define FFD 1024
#define LN_EPS 1e-5f
#define QSCALE 0.17677669529663687f  // 1/sqrt(32)

typedef __bf16 bf16x8 __attribute__((ext_vector_type(8)));
typedef float f32x4 __attribute__((ext_vector_type(4)));
typedef unsigned short u16x8 __attribute__((ext_vector_type(8)));

__device__ __forceinline__ unsigned short f2bf(float f) {
    unsigned u = __builtin_bit_cast(unsigned, f);
    u += 0x7fff + ((u >> 16) & 1);   // RNE
    return (unsigned short)(u >> 16);
}
__device__ __forceinline__ float bf2f(unsigned short h) {
    unsigned u = ((unsigned)h) << 16;
    return __builtin_bit_cast(float, u);
}
__device__ __forceinline__ void gload16(const unsigned short* g, unsigned short* l) {
    __builtin_amdgcn_global_load_lds(
        (const __attribute__((address_space(1))) unsigned int*)(const void*)g,
        (__attribute__((address_space(3))) unsigned int*)(void*)l, 16, 0, 0);
}

// ---------------- LayerNorm: one wave per token, fp32 in -> bf16 out -------
__global__ void ln_kernel(const float* __restrict__ x, const float* __restrict__ g,
                          const float* __restrict__ b, unsigned short* __restrict__ out) {
    int wave = threadIdx.x >> 6;
    int lane = threadIdx.x & 63;
    int tok = blockIdx.x * 4 + wave;
    const float4 v = ((const float4*)(x + (size_t)tok * CC))[lane];
    float s  = v.x + v.y + v.z + v.w;
    float ss = v.x * v.x + v.y * v.y + v.z * v.z + v.w * v.w;
    #pragma unroll
    for (int o = 32; o > 0; o >>= 1) { s += __shfl_xor(s, o); ss += __shfl_xor(ss, o); }
    float m   = s * (1.0f / CC);
    float var = ss * (1.0f / CC) - m * m;
    float r   = rsqrtf(var + LN_EPS);
    float4 gv = ((const float4*)g)[lane];
    float4 bv = ((const float4*)b)[lane];
    ushort4 o4;
    o4.x = f2bf((v.x - m) * r * gv.x + bv.x);
    o4.y = f2bf((v.y - m) * r * gv.y + bv.y);
    o4.z = f2bf((v.z - m) * r * gv.z + bv.z);
    o4.w = f2bf((v.w - m) * r * gv.w + bv.w);
    ((ushort4*)(out + (size_t)tok * CC))[lane] = o4;
}

// ---------------- Merged setup: all weight transposes + bias fuse ----------
__global__ void setup_kernel(const float* __restrict__ wq, const float* __restrict__ wk,
                             const float* __restrict__ wv, const float* __restrict__ wo,
                             const float* __restrict__ w1, const float* __restrict__ w2,
                             const float* __restrict__ bq, const float* __restrict__ bk,
                             const float* __restrict__ bv,
                             unsigned short* __restrict__ wt_qkv, unsigned short* __restrict__ wo_t,
                             unsigned short* __restrict__ w1_t, unsigned short* __restrict__ w2_t,
                             float* __restrict__ bqkv) {
    int id = blockIdx.x;
    int t = threadIdx.x;
    if (id == 192) {
        bqkv[t]       = bq[t] * QSCALE;
        bqkv[256 + t] = bk[t];
        bqkv[512 + t] = bv[t];
        return;
    }
    const float* src; unsigned short* dst;
    int Kd, N, rowoff = 0, bx, by; float scale = 1.0f;
    if (id < 16)       { src = wq; dst = wt_qkv; Kd = 256;  N = 256;  scale = QSCALE; int l = id;       bx = l & 3;  by = l >> 2; }
    else if (id < 32)  { src = wk; dst = wt_qkv; Kd = 256;  N = 256;  rowoff = 256;   int l = id - 16;  bx = l & 3;  by = l >> 2; }
    else if (id < 48)  { src = wv; dst = wt_qkv; Kd = 256;  N = 256;  rowoff = 512;   int l = id - 32;  bx = l & 3;  by = l >> 2; }
    else if (id < 64)  { src = wo; dst = wo_t;   Kd = 256;  N = 256;                  int l = id - 48;  bx = l & 3;  by = l >> 2; }
    else if (id < 128) { src = w1; dst = w1_t;   Kd = 256;  N = 1024;                 int l = id - 64;  bx = l & 15; by = l >> 4; }
    else               { src = w2; dst = w2_t;   Kd = 1024; N = 256;                  int l = id - 128; bx = l & 3;  by = l >> 2; }
    int n0 = bx * 64, k0 = by * 64;
    __shared__ float tile[64][65];
    int cc = t & 63, rb = t >> 6;
    #pragma unroll
    for (int i = 0; i < 16; i++) {
        int r = rb + i * 4;
        tile[r][cc] = src[(size_t)(k0 + r) * N + n0 + cc];
    }
    __syncthreads();
    int n = t >> 2;
    #pragma unroll
    for (int i = 0; i < 8; i++) {
        int p = (t & 3) + i * 4;
        unsigned lo = f2bf(tile[2 * p][n] * scale);
        unsigned hi = f2bf(tile[2 * p + 1][n] * scale);
        *(unsigned*)(dst + (size_t)(rowoff + n0 + n) * Kd + k0 + 2 * p) = lo | (hi << 16);
    }
}

// ---------------- 2-phase double-buffered bf16 MFMA GEMM, BK=64 ------------
template<int BM, int BN, int KD, int ACT, bool ADD_RES, bool OUT_BF16>
__global__ __launch_bounds__(256) void gemm_db(
    const unsigned short* __restrict__ A, const unsigned short* __restrict__ Bt,
    const float* __restrict__ bias, const float* __restrict__ res,
    void* __restrict__ Cm, int N) {
    constexpr int WM = BM / 2, WN = BN / 2;
    constexpr int MF = WM / 16, NF = WN / 16;
    constexpr int NIT = KD / 64;
    __shared__ unsigned short lds[2][(BM + BN) * 64];
    const int t = threadIdx.x;
    const int lane = t & 63, w = t >> 6;
    const int wr = w >> 1, wc = w & 1;
    const int bm = blockIdx.y * BM, bn = blockIdx.x * BN;
    const int fr = lane & 15, sq = lane >> 4;

    auto stage = [&](int it, int buf) {
        unsigned short* La = lds[buf];
        unsigned short* Lb = lds[buf] + BM * 64;
        #pragma unroll
        for (int i = 0; i < BM * 8 / 256; i++) {       // 2 slabs x BM x 4 chunks
            int c = t + i * 256;
            int kk = c / (BM * 4), r = (c % (BM * 4)) >> 2, jj = c & 3;
            gload16(A + (size_t)(bm + r) * KD + it * 64 + kk * 32 + jj * 8, La + c * 8);
        }
        #pragma unroll
        for (int i = 0; i < BN * 8 / 256; i++) {
            int c = t + i * 256;
            int kk = c / (BN * 4), r = (c % (BN * 4)) >> 2, jj = c & 3;
            gload16(Bt + (size_t)(bn + r) * KD + it * 64 + kk * 32 + jj * 8, Lb + c * 8);
        }
    };

    f32x4 acc[MF][NF] = {};
    stage(0, 0);
    for (int it = 0; it < NIT; ++it) {
        const int buf = it & 1;
        __syncthreads();                    // drains stage(it)
        if (it + 1 < NIT) stage(it + 1, buf ^ 1);
        #pragma unroll
        for (int kk = 0; kk < 2; kk++) {
            const char* La = (const char*)(lds[buf]) + kk * BM * 64;
            const char* Lb = (const char*)(lds[buf] + BM * 64) + kk * BN * 64;
            bf16x8 af[MF], bfr[NF];
            #pragma unroll
            for (int i = 0; i < MF; i++)
                af[i] = *(const bf16x8*)(La + (wr * WM + i * 16 + fr) * 64 + sq * 16);
            #pragma unroll
            for (int j = 0; j < NF; j++)
                bfr[j] = *(const bf16x8*)(Lb + (wc * WN + j * 16 + fr) * 64 + sq * 16);
            #pragma unroll
            for (int i = 0; i < MF; i++)
                #pragma unroll
                for (int j = 0; j < NF; j++)
                    acc[i][j] = __builtin_amdgcn_mfma_f32_16x16x32_bf16(af[i], bfr[j], acc[i][j], 0, 0, 0);
        }
    }
    #pragma unroll
    for (int i = 0; i < MF; i++) {
        int row0 = bm + wr * WM + i * 16 + sq * 4;
        #pragma unroll
        for (int j = 0; j < NF; j++) {
            int col = bn + wc * WN + j * 16 + fr;
            float bvv = bias[col];
            #pragma unroll
            for (int r = 0; r < 4; r++) {
                float v = acc[i][j][r] + bvv;
                if constexpr (ACT == 1) v = 0.5f * v * (1.0f + erff(v * 0.70710678118654752f));
                if constexpr (ADD_RES) v += res[(size_t)(row0 + r) * N + col];
                if constexpr (OUT_BF16)
                    ((unsigned short*)Cm)[(size_t)(row0 + r) * N + col] = f2bf(v);
                else
                    ((float*)Cm)[(size_t)(row0 + r) * N + col] = v;
            }
        }
    }
}

// ---------------- MFMA neighborhood attention ------------------------------
// DIL=2 => 4 independent 32x32 parity lattices, each plain clamped 7x7 window
// attention. Block = (parity, 4x4 query tile, head-half); 4 waves = 4 heads.
// Keys = 10x10 lattice window (100, padded to 112/128).
// Scores: C[key][q] = mfma(A=K-frag, B=Q-frag) per 16-key chunk (7 chunks).
// Bias+mask: per-tile LDS index table -> LDS rpb copy (slot 169 = -1e30).
// PV: O[q][d] = mfma(A=P-frag from LDS, B=V^T-frag from LDS V-transpose).
__global__ __launch_bounds__(256) void attn_mfma(
    const unsigned short* __restrict__ qkv, const float* __restrict__ rpb,
    unsigned short* __restrict__ ctx) {
    __shared__ __align__(16) unsigned short VT[128][136];   // V^T: [local ch][key] keys 0..127 (100..127 zero)
    __shared__ __align__(16) unsigned short Pl[4][16][136]; // P per wave: [q][key] keys 0..127
    __shared__ unsigned short tbl[16][112];                 // bias idx or 169 (invalid)
    __shared__ float rpbl[4][172];                          // per-head rpb; [169] = -1e30

    const int t = threadIdx.x;
    const int lane = t & 63, w = t >> 6;
    const int fr = lane & 15, sq = lane >> 4;
    const int bid = blockIdx.x;
    const int p = bid & 3, tile = (bid >> 2) & 63, hb = bid >> 8;
    const int ri = p >> 1, rj = p & 1;
    const int tgi = (tile >> 3) * 4, tgj = (tile & 7) * 4;
    const int kgi0 = min(max(tgi - 3, 0), 22);
    const int kgj0 = min(max(tgj - 3, 0), 22);
    const int head = hb * 4 + w;

    // --- stage rpb rows for this block's 4 heads (+ sentinel)
    for (int i = lane; i < 169; i += 64)
        rpbl[w][i] = rpb[head * 169 + i];
    if (lane == 0) rpbl[w][169] = -1e30f;

    // --- bias/mask index table, shared by the 4 heads (head-independent)
    for (int e = t; e < 16 * 112; e += 256) {
        int q = e / 112, kk = e % 112;
        unsigned short idx = 169;
        if (kk < 100) {
            int kr = kk / 10, kc = kk % 10;
            int qgi = tgi + (q >> 2), qgj = tgj + (q & 3);
            int kgi = kgi0 + kr, kgj = kgj0 + kc;
            int si = min(max(qgi - 3, 0), 25), sj = min(max(qgj - 3, 0), 25);
            if (kgi >= si && kgi <= si + 6 && kgj >= sj && kgj <= sj + 6)
                idx = (unsigned short)((kgi - qgi + 6) * 13 + (kgj - qgj + 6));
        }
        tbl[q][kk] = idx;
    }

    // --- stage V^T for this block's 128 channels: 100 keys x 16 chunks of 8ch
    for (int c0 = t; c0 < 1600; c0 += 256) {
        int key = c0 >> 4, ch8 = c0 & 15;
        int kr = key / 10, kc = key % 10;
        int kt = ((kgi0 + kr) * 2 + ri) * 64 + (kgj0 + kc) * 2 + rj;
        u16x8 vv = *(const u16x8*)(qkv + (size_t)kt * 768 + 512 + hb * 128 + ch8 * 8);
        #pragma unroll
        for (int e = 0; e < 8; e++) VT[ch8 * 8 + e][key] = vv[e];
    }
    // zero V^T pad keys 100..127 (avoid Inf*0=NaN in PV MFMA)
    for (int c0 = t; c0 < 128 * 14; c0 += 256) {
        int row = c0 / 14, cp = c0 % 14;
        *(unsigned*)&VT[row][100 + cp * 2] = 0;
    }
    __syncthreads();

    // --- Q fragment: A/B-frag layout = [row/col = lane&15][k = (lane>>4)*8+e]
    const int qtok = ((tgi + (fr >> 2)) * 2 + ri) * 64 + (tgj + (fr & 3)) * 2 + rj;
    bf16x8 qf = *(const bf16x8*)(qkv + (size_t)qtok * 768 + head * 32 + sq * 8);

    // --- scores: 7 chunks of 16 keys; one mfma each (K=32=HD)
    f32x4 sc[7];
    #pragma unroll
    for (int c = 0; c < 7; c++) {
        int kk = c * 16 + fr;
        if (kk > 99) kk = 99;                       // dup, masked by tbl
        int kr = kk / 10, kc = kk % 10;
        int kt = ((kgi0 + kr) * 2 + ri) * 64 + (kgj0 + kc) * 2 + rj;
        bf16x8 kf = *(const bf16x8*)(qkv + (size_t)kt * 768 + 256 + head * 32 + sq * 8);
        f32x4 z = {0.0f, 0.0f, 0.0f, 0.0f};
        sc[c] = __builtin_amdgcn_mfma_f32_16x16x32_bf16(kf, qf, z, 0, 0, 0);
    }
    // lane holds scores for query fr, keys {c*16 + 4*sq + r}
    #pragma unroll
    for (int c = 0; c < 7; c++)
        #pragma unroll
        for (int r = 0; r < 4; r++) {
            int idx = tbl[fr][c * 16 + 4 * sq + r];
            sc[c][r] += rpbl[w][idx];
        }

    // --- softmax over the query column (28 in-lane + 4 lanes via shfl)
    float mx = -1e30f;
    #pragma unroll
    for (int c = 0; c < 7; c++)
        #pragma unroll
        for (int r = 0; r < 4; r++) mx = fmaxf(mx, sc[c][r]);
    mx = fmaxf(mx, __shfl_xor(mx, 16));
    mx = fmaxf(mx, __shfl_xor(mx, 32));
    float sum = 0.0f;
    #pragma unroll
    for (int c = 0; c < 7; c++)
        #pragma unroll
        for (int r = 0; r < 4; r++) {
            sc[c][r] = __expf(sc[c][r] - mx);
            sum += sc[c][r];
        }
    sum += __shfl_xor(sum, 16);
    sum += __shfl_xor(sum, 32);
    float inv = 1.0f / sum;

    // --- P -> LDS (bf16), keys 112..127 zeroed
    #pragma unroll
    for (int c = 0; c < 7; c++)
        #pragma unroll
        for (int r = 0; r < 4; r++)
            Pl[w][fr][c * 16 + 4 * sq + r] = f2bf(sc[c][r] * inv);
    *(unsigned long long*)&Pl[w][fr][112 + sq * 4] = 0ull;

    // --- PV: 4 key-chunks of 32; A = P-frag, B = V^T-frag; C[q][d]
    f32x4 o0 = {0, 0, 0, 0}, o1 = {0, 0, 0, 0};
    #pragma unroll
    for (int m = 0; m < 4; m++) {
        bf16x8 pf = *(const bf16x8*)(&Pl[w][fr][m * 32 + sq * 8]);
        bf16x8 v0 = *(const bf16x8*)(&VT[w * 32 + fr][m * 32 + sq * 8]);
        bf16x8 v1 = *(const bf16x8*)(&VT[w * 32 + 16 + fr][m * 32 + sq * 8]);
        o0 = __builtin_amdgcn_mfma_f32_16x16x32_bf16(pf, v0, o0, 0, 0, 0);
        o1 = __builtin_amdgcn_mfma_f32_16x16x32_bf16(pf, v1, o1, 0, 0, 0);
    }
    // C layout: col(dim)=lane&15, row(query)=4*sq+r
    #pragma unroll
    for (int r = 0; r < 4; r++) {
        int tok = ((tgi + sq) * 2 + ri) * 64 + (tgj + r) * 2 + rj;
        ctx[(size_t)tok * 256 + head * 32 + fr]      = f2bf(o0[r]);
        ctx[(size_t)tok * 256 + head * 32 + 16 + fr] = f2bf(o1[r]);
    }
}

extern "C" void kernel_launch(void* const* d_in, const int* in_sizes, int n_in,
                              void* d_out, int out_size, void* d_ws, size_t ws_size,
                              hipStream_t stream) {
    const float* x     = (const float*)d_in[0];
    const float* ln1_g = (const float*)d_in[1];
    const float* ln1_b = (const float*)d_in[2];
    const float* wq    = (const float*)d_in[3];
    const float* bq    = (const float*)d_in[4];
    const float* wk    = (const float*)d_in[5];
    const float* bk    = (const float*)d_in[6];
    const float* wv    = (const float*)d_in[7];
    const float* bv    = (const float*)d_in[8];
    const float* rpb   = (const float*)d_in[9];
    const float* wo    = (const float*)d_in[10];
    const float* bo    = (const float*)d_in[11];
    const float* ln2_g = (const float*)d_in[12];
    const float* ln2_b = (const float*)d_in[13];
    const float* w1    = (const float*)d_in[14];
    const float* b1    = (const float*)d_in[15];
    const float* w2    = (const float*)d_in[16];
    const float* b2    = (const float*)d_in[17];

    char* wsb = (char*)d_ws;
    unsigned short* hs_bf  = (unsigned short*)(wsb);                    // 2 MB
    unsigned short* qkv_bf = (unsigned short*)(wsb + (2u << 20));       // 6 MB
    unsigned short* ctx_bf = (unsigned short*)(wsb + (8u << 20));       // 2 MB
    float*          hs2    = (float*)(wsb + (10u << 20));               // 4 MB
    unsigned short* y1_bf  = (unsigned short*)(wsb + (14u << 20));      // 2 MB
    unsigned short* gm_bf  = (unsigned short*)(wsb + (16u << 20));      // 8 MB
    unsigned short* wt_qkv = (unsigned short*)(wsb + (24u << 20));      // 768x256
    unsigned short* wo_t   = wt_qkv + 768 * 256;                        // 256x256
    unsigned short* w1_t   = wo_t + 256 * 256;                          // 1024x256
    unsigned short* w2_t   = w1_t + 1024 * 256;                         // 256x1024
    float*          bqkv   = (float*)(w2_t + 256 * 1024);               // 768

    // 0. merged weight transpose/convert + bias fuse
    setup_kernel<<<193, 256, 0, stream>>>(wq, wk, wv, wo, w1, w2, bq, bk, bv,
                                          wt_qkv, wo_t, w1_t, w2_t, bqkv);
    // 1. hs = LN1(x)
    ln_kernel<<<NTOK / 4, 256, 0, stream>>>(x, ln1_g, ln1_b, hs_bf);
    // 2. fused QKV: [4096,768] = hs @ [wq|wk|wv]
    gemm_db<64, 64, 256, 0, false, true><<<dim3(12, 64), 256, 0, stream>>>(
        hs_bf, wt_qkv, bqkv, nullptr, qkv_bf, 768);
    // 3. neighborhood attention (MFMA, parity-lattice tiles)
    attn_mfma<<<512, 256, 0, stream>>>(qkv_bf, rpb, ctx_bf);
    // 4. hs2 = x + ctx@wo + bo  (fp32)
    gemm_db<32, 64, 256, 0, true, false><<<dim3(4, 128), 256, 0, stream>>>(
        ctx_bf, wo_t, bo, x, hs2, 256);
    // 5. y1 = LN2(hs2)
    ln_kernel<<<NTOK / 4, 256, 0, stream>>>(hs2, ln2_g, ln2_b, y1_bf);
    // 6. gmid = gelu(y1@w1 + b1)
    gemm_db<64, 64, 256, 1, false, true><<<dim3(16, 64), 256, 0, stream>>>(
        y1_bf, w1_t, b1, nullptr, gm_bf, 1024);
    // 7. out = hs2 + gmid@w2 + b2  (fp32)
    gemm_db<32, 64, 1024, 0, true, false><<<dim3(4, 128), 256, 0, stream>>>(
        gm_bf, w2_t, b2, hs2, (float*)d_out, 256);
}